// Round 3
// baseline (263.448 us; speedup 1.0000x reference)
//
#include <hip/hip_runtime.h>
#include <hip/hip_bf16.h>
#include <stdint.h>

typedef unsigned short ushort_t;

__device__ __forceinline__ float bf2f(ushort_t u) {
    union { unsigned int i; float f; } v;
    v.i = ((unsigned int)u) << 16;
    return v.f;
}

__device__ __forceinline__ ushort_t f2bf(float f) {
    __hip_bfloat16 h = __float2bfloat16(f);
    return *reinterpret_cast<ushort_t*>(&h);
}

// Robust timestep read for the bf16-input case (handles a stray fp32 scalar).
__device__ __forceinline__ float read_ts_robust(const void* ts) {
    float bf = bf2f(((const ushort_t*)ts)[0]);
    float ab = fabsf(bf);
    if (isfinite(bf) && ab > 1e-6f && ab < 1e3f) return bf;
    return ((const float*)ts)[0];
}

// Detect input dtype from in_W1 (bound 1/sqrt(4096)=0.0156). Even-indexed
// ushorts: true bf16 -> |v| < 0.016 always; fp32 low-halves -> random bits,
// ~50% have |v| >= 1 (or NaN). flag: 1 = fp32 inputs, 0 = bf16 inputs.
__global__ void detect_kernel(const ushort_t* __restrict__ W, int* __restrict__ flag) {
    if (threadIdx.x == 0 && blockIdx.x == 0) {
        int cnt = 0;
        for (int k = 0; k < 64; k++) {
            float v = bf2f(W[2 * k]);
            if (!(fabsf(v) < 1.0f)) cnt++;  // counts NaN too
        }
        *flag = (cnt >= 8) ? 1 : 0;
    }
}

// Build the 2049-float input vector: [x (2048), timestep]
__global__ void prep_x_kernel(const ushort_t* __restrict__ xb,
                              const void* __restrict__ ts,
                              float* __restrict__ xf, int n,
                              const int* __restrict__ flag) {
    int f = *flag;
    int i = blockIdx.x * blockDim.x + threadIdx.x;
    if (i < n) xf[i] = f ? ((const float*)xb)[i] : bf2f(xb[i]);
    if (i == 0) xf[n] = f ? ((const float*)ts)[0] : read_ts_robust(ts);
}

// GEMV: y[row] = b[row] + sum_j W[row, j] * x[j]   (W row-major; x fp32)
// One wave per row, 4 rows/block. Dual dtype path selected by *flag.
__global__ __launch_bounds__(256) void gemv_kernel(
    const ushort_t* __restrict__ W, const ushort_t* __restrict__ B,
    const float* __restrict__ x, float* __restrict__ y,
    void* __restrict__ outbuf, int out_off, int rows, int cols, int relu,
    const int* __restrict__ flag)
{
    int f = *flag;
    int wave = threadIdx.x >> 6;
    int lane = threadIdx.x & 63;
    int row = blockIdx.x * 4 + wave;
    if (row >= rows) return;

    float sum = 0.0f;

    if (f) {
        // ---- fp32 weights ----
        const float* w = (const float*)W + (size_t)row * (size_t)cols;
        int mis = (int)(((uintptr_t)w & 15) >> 2);  // 0..3 elements
        int start = (4 - mis) & 3;
        if (start > cols) start = cols;
        if (lane < start) sum += w[lane] * x[lane];
        int nv = (cols - start) >> 2;
        const float4* wv = (const float4*)(w + start);
        for (int g = lane; g < nv; g += 64) {
            float4 u = wv[g];
            const float* xp = x + start + g * 4;
            sum += u.x * xp[0] + u.y * xp[1] + u.z * xp[2] + u.w * xp[3];
        }
        int t = start + nv * 4 + lane;
        if (t < cols) sum += w[t] * x[t];
    } else {
        // ---- bf16 weights ----
        const ushort_t* w = W + (size_t)row * (size_t)cols;
        int mis = (int)(((uintptr_t)w & 15) >> 1);  // 0..7 elements
        int start = (8 - mis) & 7;
        if (start > cols) start = cols;
        if (lane < start) sum += bf2f(w[lane]) * x[lane];
        int nv = (cols - start) >> 3;
        const uint4* wv = (const uint4*)(w + start);
        for (int g = lane; g < nv; g += 64) {
            uint4 u = wv[g];
            const float* xp = x + start + g * 8;
            sum += bf2f((ushort_t)(u.x & 0xffff)) * xp[0];
            sum += bf2f((ushort_t)(u.x >> 16))    * xp[1];
            sum += bf2f((ushort_t)(u.y & 0xffff)) * xp[2];
            sum += bf2f((ushort_t)(u.y >> 16))    * xp[3];
            sum += bf2f((ushort_t)(u.z & 0xffff)) * xp[4];
            sum += bf2f((ushort_t)(u.z >> 16))    * xp[5];
            sum += bf2f((ushort_t)(u.w & 0xffff)) * xp[6];
            sum += bf2f((ushort_t)(u.w >> 16))    * xp[7];
        }
        int t = start + nv * 8 + lane;
        if (t < cols) sum += bf2f(w[t]) * x[t];
    }

    #pragma unroll
    for (int off = 32; off > 0; off >>= 1)
        sum += __shfl_down(sum, off);

    if (lane == 0) {
        float r = sum + (f ? ((const float*)B)[row] : bf2f(B[row]));
        if (relu) r = fmaxf(r, 0.0f);
        if (y) y[row] = r;
        if (outbuf) {
            if (f) ((float*)outbuf)[out_off + row] = r;
            else   ((ushort_t*)outbuf)[out_off + row] = f2bf(r);
        }
    }
}

// RK4-3/8 step of the CPG ODE. n=32, state = [a, a_dot, ph] (96 elements).
// Reference quirks matched exactly:
//   dy = concat([a_dot, phase_dots, a_dd])  -> phase_dots integrates slot [n:2n]
//   cpg_out uses a = new_state[:n], ph = new_state[n:2n]
__global__ __launch_bounds__(64) void ode_kernel(
    const ushort_t* __restrict__ state, const void* __restrict__ ts,
    const float* __restrict__ params, float* __restrict__ cpg,
    void* __restrict__ out_state, const int* __restrict__ flag)
{
    const float CONV = 1000.0f;
    __shared__ float s_y[96];
    int f = *flag;
    int t = threadIdx.x;
    bool act = (t < 32);
    int i = t;
    float h = f ? ((const float*)ts)[0] : read_ts_robust(ts);

    float ia = 0.f, ifr = 0.f;
    float cwr[32], pbr[32];
    float y0a = 0.f, y0b = 0.f, y0c = 0.f;

    if (act) {
        ia = params[i];
        ifr = params[32 + i];
        #pragma unroll
        for (int j = 0; j < 32; j++) {
            cwr[j] = params[64 + i * 32 + j];
            pbr[j] = params[1088 + i * 32 + j];
        }
        const float* sf = (const float*)state;
        y0a = f ? sf[i]      : bf2f(state[i]);
        y0b = f ? sf[32 + i] : bf2f(state[32 + i]);
        y0c = f ? sf[64 + i] : bf2f(state[64 + i]);
        s_y[i] = y0a; s_y[32 + i] = y0b; s_y[64 + i] = y0c;
    }
    __syncthreads();

    float k1a=0,k1b=0,k1c=0, k2a=0,k2b=0,k2c=0, k3a=0,k3b=0,k3c=0, k4a=0,k4b=0,k4c=0;

    auto evalf = [&](float& fa, float& fb, float& fc) {
        float a  = s_y[i];
        float ad = s_y[32 + i];
        float ph = s_y[64 + i];
        float ssum = 0.0f;
        #pragma unroll
        for (int j = 0; j < 32; j++) {
            ssum += cwr[j] * sinf(s_y[64 + j] - ph - pbr[j]);
        }
        fa = ad;                                    // d(a)/dt -> slot [0:n]
        fb = ifr + a * ssum;                        // phase_dots -> slot [n:2n]
        fc = CONV * (CONV * 0.25f * (ia - a) - ad); // a_dd -> slot [2n:3n]
    };

    if (act) evalf(k1a, k1b, k1c);
    __syncthreads();
    if (act) {
        s_y[i]      = y0a + h * k1a / 3.0f;
        s_y[32 + i] = y0b + h * k1b / 3.0f;
        s_y[64 + i] = y0c + h * k1c / 3.0f;
    }
    __syncthreads();
    if (act) evalf(k2a, k2b, k2c);
    __syncthreads();
    if (act) {
        s_y[i]      = y0a + h * (k2a - k1a / 3.0f);
        s_y[32 + i] = y0b + h * (k2b - k1b / 3.0f);
        s_y[64 + i] = y0c + h * (k2c - k1c / 3.0f);
    }
    __syncthreads();
    if (act) evalf(k3a, k3b, k3c);
    __syncthreads();
    if (act) {
        s_y[i]      = y0a + h * (k1a - k2a + k3a);
        s_y[32 + i] = y0b + h * (k1b - k2b + k3b);
        s_y[64 + i] = y0c + h * (k1c - k2c + k3c);
    }
    __syncthreads();
    if (act) evalf(k4a, k4b, k4c);

    if (act) {
        float na = y0a + h * 0.125f * (k1a + 3.0f * (k2a + k3a) + k4a);
        float nb = y0b + h * 0.125f * (k1b + 3.0f * (k2b + k3b) + k4b);
        float nc = y0c + h * 0.125f * (k1c + 3.0f * (k2c + k3c) + k4c);
        if (f) {
            float* fo = (float*)out_state;
            fo[i] = na; fo[32 + i] = nb; fo[64 + i] = nc;
        } else {
            ushort_t* bo = (ushort_t*)out_state;
            bo[i] = f2bf(na); bo[32 + i] = f2bf(nb); bo[64 + i] = f2bf(nc);
        }
        // cpg_out: a = new_state[:32], ph = new_state[32:64]  (reference quirk)
        cpg[i]      = na * cosf(nb);
        cpg[32 + i] = na * sinf(nb);
    }
}

extern "C" void kernel_launch(void* const* d_in, const int* in_sizes, int n_in,
                              void* d_out, int out_size, void* d_ws, size_t ws_size,
                              hipStream_t stream) {
    const ushort_t* state = (const ushort_t*)d_in[0];   // 96
    const ushort_t* x     = (const ushort_t*)d_in[1];   // 2048
    const void*     ts    = d_in[2];                    // 1
    const ushort_t* inW0  = (const ushort_t*)d_in[3];   // 4096 x 2049
    const ushort_t* inb0  = (const ushort_t*)d_in[4];   // 4096
    const ushort_t* inW1  = (const ushort_t*)d_in[5];   // 4096 x 4096
    const ushort_t* inb1  = (const ushort_t*)d_in[6];   // 4096
    const ushort_t* inW2  = (const ushort_t*)d_in[7];   // 2112 x 4096
    const ushort_t* inb2  = (const ushort_t*)d_in[8];   // 2112
    const ushort_t* oW0   = (const ushort_t*)d_in[9];   // 2048 x 64
    const ushort_t* ob0   = (const ushort_t*)d_in[10];  // 2048
    const ushort_t* oW1   = (const ushort_t*)d_in[11];  // 2048 x 2048
    const ushort_t* ob1   = (const ushort_t*)d_in[12];  // 2048
    const ushort_t* oW2   = (const ushort_t*)d_in[13];  // 1024 x 2048
    const ushort_t* ob2   = (const ushort_t*)d_in[14];  // 1024

    float* ws  = (float*)d_ws;
    float* xf  = ws;            // 2049 (pad to 2064)
    float* h0  = ws + 2064;     // 4096
    float* h1  = ws + 6160;     // 4096
    float* pr  = ws + 10256;    // 2112
    float* cpg = ws + 12368;    // 64
    float* g0  = ws + 12432;    // 2048
    float* g1  = ws + 14480;    // 2048
    int*   flg = (int*)(ws + 16536);

    detect_kernel<<<1, 64, 0, stream>>>(inW1, flg);
    prep_x_kernel<<<9, 256, 0, stream>>>(x, ts, xf, 2048, flg);
    gemv_kernel<<<1024, 256, 0, stream>>>(inW0, inb0, xf, h0, nullptr, 0, 4096, 2049, 1, flg);
    gemv_kernel<<<1024, 256, 0, stream>>>(inW1, inb1, h0, h1, nullptr, 0, 4096, 4096, 1, flg);
    gemv_kernel<<<528,  256, 0, stream>>>(inW2, inb2, h1, pr, nullptr, 0, 2112, 4096, 0, flg);
    ode_kernel<<<1, 64, 0, stream>>>(state, ts, pr, cpg, d_out, flg);
    gemv_kernel<<<512,  256, 0, stream>>>(oW0, ob0, cpg, g0, nullptr, 0, 2048, 64, 1, flg);
    gemv_kernel<<<512,  256, 0, stream>>>(oW1, ob1, g0, g1, nullptr, 0, 2048, 2048, 1, flg);
    gemv_kernel<<<256,  256, 0, stream>>>(oW2, ob2, g1, nullptr, d_out, 96, 1024, 2048, 0, flg);
}

// Round 4
// 214.142 us; speedup vs baseline: 1.2303x; 1.2303x over previous
//
#include <hip/hip_runtime.h>
#include <stdint.h>

// ---------------------------------------------------------------------------
// GEMV: y[row] = (relu?)(b[row] + W[row,:] . x)
// One 256-thread block per row. fp32 weights streamed as float4, 4 in flight
// per thread. TS=1: last column is multiplied by ts[0] (fuses the [x, t]
// concat of the input layer).
// ---------------------------------------------------------------------------
template<int RELU, int TS>
__global__ __launch_bounds__(256) void gemv_k(
    const float* __restrict__ W, const float* __restrict__ B,
    const float* __restrict__ x, const float* __restrict__ ts,
    float* __restrict__ y, int cols)
{
    int tid = threadIdx.x;
    int row = blockIdx.x;
    int n = TS ? cols - 1 : cols;
    const float* w = W + (size_t)row * (size_t)cols;

    // row base may be misaligned for odd strides (2049): scalar head to 16B
    int mis = (int)(((uintptr_t)w >> 2) & 3);
    int start = (4 - mis) & 3;
    if (start > n) start = n;

    float sum = 0.0f;
    if (tid < start) sum += w[tid] * x[tid];

    int nv = (n - start) >> 2;
    const float4* wv = (const float4*)(w + start);
    const float* xs = x + start;

    int g = tid;
    for (; g + 768 < nv; g += 1024) {
        float4 u0 = wv[g];
        float4 u1 = wv[g + 256];
        float4 u2 = wv[g + 512];
        float4 u3 = wv[g + 768];
        const float* x0 = xs + 4 * g;
        const float* x1 = xs + 4 * (g + 256);
        const float* x2 = xs + 4 * (g + 512);
        const float* x3 = xs + 4 * (g + 768);
        sum += u0.x * x0[0] + u0.y * x0[1] + u0.z * x0[2] + u0.w * x0[3];
        sum += u1.x * x1[0] + u1.y * x1[1] + u1.z * x1[2] + u1.w * x1[3];
        sum += u2.x * x2[0] + u2.y * x2[1] + u2.z * x2[2] + u2.w * x2[3];
        sum += u3.x * x3[0] + u3.y * x3[1] + u3.z * x3[2] + u3.w * x3[3];
    }
    for (; g < nv; g += 256) {
        float4 u = wv[g];
        const float* xp = xs + 4 * g;
        sum += u.x * xp[0] + u.y * xp[1] + u.z * xp[2] + u.w * xp[3];
    }
    int t = start + nv * 4 + tid;
    if (t < n) sum += w[t] * x[t];
    if (TS && tid == 0) sum += w[n] * ts[0];

    // 256 -> 1 reduction: wave64 shuffle, then LDS across the 4 waves
    #pragma unroll
    for (int off = 32; off > 0; off >>= 1) sum += __shfl_down(sum, off);
    __shared__ float red[4];
    if ((tid & 63) == 0) red[tid >> 6] = sum;
    __syncthreads();
    if (tid == 0) {
        float r = red[0] + red[1] + red[2] + red[3] + B[row];
        if (RELU) r = fmaxf(r, 0.0f);
        y[row] = r;
    }
}

// ---------------------------------------------------------------------------
// RK4-3/8 step of the CPG ODE. n=32, params = [ia(32), ifr(32), cw(1024),
// pb(1024)]. Reference quirks preserved exactly (verified passing in R3):
//   dy = concat([a_dot, phase_dots, a_dd]) -> phase_dots integrates slot [n:2n]
//   cpg_out uses a = new_state[:n], "ph" = new_state[n:2n]
// Optimizations vs R3: coalesced LDS staging of cw/pb (was 64 stride-128B
// scalar loads/lane = the 46.5us), sincos(pb) computed by all 64 threads in
// parallel at staging, inner loop trig via angle-addition -> pure FMA.
// ---------------------------------------------------------------------------
__global__ __launch_bounds__(64) void ode_k(
    const float* __restrict__ state, const float* __restrict__ ts,
    const float* __restrict__ params, float* __restrict__ cpg,
    float* __restrict__ out_state)
{
    const float CONV = 1000.0f;
    __shared__ float s_cw[32 * 33];   // +1 pad: lane i row i reads conflict-free
    __shared__ float s_spb[32 * 33];
    __shared__ float s_cpb[32 * 33];
    __shared__ float s_s[32], s_c[32];
    int tid = threadIdx.x;

    // coalesced staging; 1024 sincos spread over 64 threads
    for (int k = tid; k < 1024; k += 64) {
        int p = k + (k >> 5);   // padded index: row k/32, col k%32
        s_cw[p] = params[64 + k];
        float pb = params[1088 + k];
        float sp, cp;
        sincosf(pb, &sp, &cp);
        s_spb[p] = sp;
        s_cpb[p] = cp;
    }
    __syncthreads();

    bool act = (tid < 32);
    int i = tid;
    float ia = 0.f, ifr = 0.f, y0a = 0.f, y0b = 0.f, y0c = 0.f;
    if (act) {
        ia  = params[i];
        ifr = params[32 + i];
        y0a = state[i];        // a
        y0b = state[32 + i];   // a_dot
        y0c = state[64 + i];   // ph
    }
    float h = ts[0];

    float k1a=0,k1b=0,k1c=0, k2a=0,k2b=0,k2c=0, k3a=0,k3b=0,k3c=0, k4a=0,k4b=0,k4c=0;

    // f(y): all threads enter (contains barriers), lanes >=32 are passive
    auto do_eval = [&](float a, float ad, float ph,
                       float& fa, float& fb, float& fc) {
        __syncthreads();   // previous read phase done before overwriting s_s/s_c
        if (act) {
            float s, c;
            sincosf(ph, &s, &c);
            s_s[i] = s; s_c[i] = c;
        }
        __syncthreads();
        if (act) {
            float si = s_s[i], ci = s_c[i];
            float ssum = 0.0f;
            #pragma unroll
            for (int j = 0; j < 32; j++) {
                float sj = s_s[j], cj = s_c[j];          // broadcast reads
                float sdp = sj * ci - cj * si;           // sin(ph_j - ph_i)
                float cdp = cj * ci + sj * si;           // cos(ph_j - ph_i)
                int p = i * 33 + j;
                float sv = sdp * s_cpb[p] - cdp * s_spb[p]; // sin(dphi - pb)
                ssum += s_cw[p] * sv;
            }
            fa = ad;                                      // -> slot [0:n]
            fb = ifr + a * ssum;                          // phase_dots -> [n:2n]
            fc = CONV * (CONV * 0.25f * (ia - a) - ad);   // a_dd -> [2n:3n]
        }
    };

    do_eval(y0a, y0b, y0c, k1a, k1b, k1c);
    do_eval(y0a + h * k1a / 3.0f,
            y0b + h * k1b / 3.0f,
            y0c + h * k1c / 3.0f, k2a, k2b, k2c);
    do_eval(y0a + h * (k2a - k1a / 3.0f),
            y0b + h * (k2b - k1b / 3.0f),
            y0c + h * (k2c - k1c / 3.0f), k3a, k3b, k3c);
    do_eval(y0a + h * (k1a - k2a + k3a),
            y0b + h * (k1b - k2b + k3b),
            y0c + h * (k1c - k2c + k3c), k4a, k4b, k4c);

    if (act) {
        float na = y0a + h * 0.125f * (k1a + 3.0f * (k2a + k3a) + k4a);
        float nb = y0b + h * 0.125f * (k1b + 3.0f * (k2b + k3b) + k4b);
        float nc = y0c + h * 0.125f * (k1c + 3.0f * (k2c + k3c) + k4c);
        out_state[i]      = na;
        out_state[32 + i] = nb;
        out_state[64 + i] = nc;
        // cpg_out: a = new_state[:32], ph = new_state[32:64] (reference quirk)
        cpg[i]      = na * cosf(nb);
        cpg[32 + i] = na * sinf(nb);
    }
}

extern "C" void kernel_launch(void* const* d_in, const int* in_sizes, int n_in,
                              void* d_out, int out_size, void* d_ws, size_t ws_size,
                              hipStream_t stream) {
    const float* state = (const float*)d_in[0];   // 96
    const float* x     = (const float*)d_in[1];   // 2048
    const float* ts    = (const float*)d_in[2];   // 1
    const float* inW0  = (const float*)d_in[3];   // 4096 x 2049
    const float* inb0  = (const float*)d_in[4];   // 4096
    const float* inW1  = (const float*)d_in[5];   // 4096 x 4096
    const float* inb1  = (const float*)d_in[6];   // 4096
    const float* inW2  = (const float*)d_in[7];   // 2112 x 4096
    const float* inb2  = (const float*)d_in[8];   // 2112
    const float* oW0   = (const float*)d_in[9];   // 2048 x 64
    const float* ob0   = (const float*)d_in[10];  // 2048
    const float* oW1   = (const float*)d_in[11];  // 2048 x 2048
    const float* ob1   = (const float*)d_in[12];  // 2048
    const float* oW2   = (const float*)d_in[13];  // 1024 x 2048
    const float* ob2   = (const float*)d_in[14];  // 1024

    float* ws  = (float*)d_ws;
    float* h0  = ws;            // 4096
    float* h1  = ws + 4096;     // 4096
    float* pr  = ws + 8192;     // 2112
    float* cpg = ws + 10304;    // 64
    float* g0  = ws + 10368;    // 2048
    float* g1  = ws + 12416;    // 2048

    float* out = (float*)d_out; // 96 (new_state) + 1024, fp32

    gemv_k<1,1><<<4096, 256, 0, stream>>>(inW0, inb0, x,   ts,      h0, 2049);
    gemv_k<1,0><<<4096, 256, 0, stream>>>(inW1, inb1, h0,  nullptr, h1, 4096);
    gemv_k<0,0><<<2112, 256, 0, stream>>>(inW2, inb2, h1,  nullptr, pr, 4096);
    ode_k<<<1, 64, 0, stream>>>(state, ts, pr, cpg, out);
    gemv_k<1,0><<<2048, 256, 0, stream>>>(oW0,  ob0,  cpg, nullptr, g0, 64);
    gemv_k<1,0><<<2048, 256, 0, stream>>>(oW1,  ob1,  g0,  nullptr, g1, 2048);
    gemv_k<0,0><<<1024, 256, 0, stream>>>(oW2,  ob2,  g1,  nullptr, out + 96, 2048);
}